// Round 8
// baseline (107.091 us; speedup 1.0000x reference)
//
#include <hip/hip_runtime.h>

#define TT 48
#define II 5
#define HID 8

typedef float float2v __attribute__((ext_vector_type(2)));

// quad_perm DPP; 0xB1 = lane^1, 0x4E = lane^2, 0x1B = lane^3; 0x141 = row_half_mirror (lane^7 in 8-lane groups)
template<int CTRL>
__device__ __forceinline__ float dppf(float v) {
    return __int_as_float(__builtin_amdgcn_update_dpp(0, __float_as_int(v), CTRL, 0xF, 0xF, true));
}
__device__ __forceinline__ float fexp2(float x){ float r; asm("v_exp_f32 %0, %1":"=v"(r):"v"(x)); return r; }
__device__ __forceinline__ float frcp(float x){ return __builtin_amdgcn_rcpf(x); }

// packed fp32 fma with weight-half broadcast via op_sel (R3-proven helpers):
// pk_lo: lo += w.lo*z.lo ; hi += w.lo*z.hi
__device__ __forceinline__ float2v pk_lo(float2v acc, float2v w, float2v z) {
    asm("v_pk_fma_f32 %0, %1, %2, %0 op_sel_hi:[0,1,1]" : "+v"(acc) : "v"(w), "v"(z));
    return acc;
}
// pk_hi: lo += w.hi*z.lo ; hi += w.hi*z.hi
__device__ __forceinline__ float2v pk_hi(float2v acc, float2v w, float2v z) {
    asm("v_pk_fma_f32 %0, %1, %2, %0 op_sel:[1,0,0] op_sel_hi:[1,1,1]" : "+v"(acc) : "v"(w), "v"(z));
    return acc;
}
// d = {w.lo*z.lo + b.lo, w.lo*z.hi + b.hi}
__device__ __forceinline__ float2v pk_lo3(float2v w, float2v z, float2v b) {
    float2v d;
    asm("v_pk_fma_f32 %0, %1, %2, %3 op_sel_hi:[0,1,1]" : "=v"(d) : "v"(w), "v"(z), "v"(b));
    return d;
}
__device__ __forceinline__ void pin2(float2v& v) { asm("" : "+v"(v)); }

// 64-thread blocks (1 wave). Lane: q = unit (0..7), slot = lane>>3 -> batch pair.
// Per lane: unit q's full weight set packed into 28 float2v (7 pairs x 4 gates),
// two independent batch recurrences in the pk halves.
// amdgpu_waves_per_eu(2,2): caps the scheduler's occupancy target at 2 waves/EU
// -> 256-VGPR budget -> weights stay register-resident (R1-R3: default heuristic
// remat'd/spilled them every step; VGPR_Count 48-64 was the smoking gun).
__global__ __attribute__((amdgpu_flat_work_group_size(64, 64), amdgpu_waves_per_eu(2, 2)))
void lstm_fused(
    const float* __restrict__ x,
    const float* __restrict__ W_ih,
    const float* __restrict__ W_hh,
    const float* __restrict__ b_ih,
    const float* __restrict__ b_hh,
    const float* __restrict__ fc_W,
    const float* __restrict__ fc_b,
    float* __restrict__ out, int B)
{
    __shared__ float s_fc[TT * HID];
    const int tid = threadIdx.x;   // 0..63
    #pragma unroll
    for (int i = tid; i < TT * HID; i += 64) s_fc[i] = fc_W[i];
    __syncthreads();

    const int q    = tid & 7;
    const int slot = tid >> 3;
    const int b0   = (blockIdx.x * 8 + slot) * 2;
    if (b0 >= B) return;

    const float L2E  = 1.44269504088896340736f;
    const float L2E2 = 2.0f * L2E;
    // i,f,o rows prescaled by -log2e (so E = exp2(s) = e^{-v}), g rows by +2log2e (E = e^{2v}).
    const float sc[4] = {-L2E, -L2E, L2E2, -L2E};

    // ---- weights: 7 pairs per gate; slots = [x0..x4, h_{q^0}..h_{q^7}] ----
    float2v P[4][7], bias[4];
    #pragma unroll
    for (int g = 0; g < 4; ++g) {
        const int row = g * 8 + q;
        const float s = sc[g];
        P[g][0] = (float2v){s * W_ih[row * II + 0], s * W_ih[row * II + 1]};
        P[g][1] = (float2v){s * W_ih[row * II + 2], s * W_ih[row * II + 3]};
        P[g][2] = (float2v){s * W_ih[row * II + 4], s * W_hh[row * HID + (q ^ 0)]};
        P[g][3] = (float2v){s * W_hh[row * HID + (q ^ 1)], s * W_hh[row * HID + (q ^ 2)]};
        P[g][4] = (float2v){s * W_hh[row * HID + (q ^ 3)], s * W_hh[row * HID + (q ^ 4)]};
        P[g][5] = (float2v){s * W_hh[row * HID + (q ^ 5)], s * W_hh[row * HID + (q ^ 6)]};
        P[g][6] = (float2v){s * W_hh[row * HID + (q ^ 7)], 0.0f};
        const float bb = s * (b_ih[row] + b_hh[row]);
        bias[g] = (float2v){bb, bb};
        #pragma unroll
        for (int j = 0; j < 7; ++j) pin2(P[g][j]);
        pin2(bias[g]);
    }

    const float2* xA = reinterpret_cast<const float2*>(x + (size_t)b0 * (TT * II));
    const float2* xB = reinterpret_cast<const float2*>(x + (size_t)(b0 + 1) * (TT * II));

    float2 curA[5], curB[5], nxtA[5], nxtB[5];   // one chunk = 10 floats = 2 steps
    #pragma unroll
    for (int k = 0; k < 5; ++k) { curA[k] = xA[k]; curB[k] = xB[k]; }

    float hA = 0.f, hB = 0.f, cA = 0.f, cB = 0.f, accA = 0.f, accB = 0.f;

    #pragma unroll 1
    for (int ch = 0; ch < 24; ++ch) {
        if (ch < 23) {
            #pragma unroll
            for (int k = 0; k < 5; ++k) { nxtA[k] = xA[(ch + 1) * 5 + k]; nxtB[k] = xB[(ch + 1) * 5 + k]; }
        }

        #pragma unroll
        for (int s2 = 0; s2 < 2; ++s2) {
            const int t = ch * 2 + s2;

            // data pairs for this step's 5 x slots ({batchA, batchB})
            float2v xs[5];
            #pragma unroll
            for (int i = 0; i < 5; ++i) {
                const int idx = s2 * 5 + i;
                const float a = (idx & 1) ? curA[idx >> 1].y : curA[idx >> 1].x;
                const float b = (idx & 1) ? curB[idx >> 1].y : curB[idx >> 1].x;
                xs[i] = (float2v){a, b};
            }

            // h gather: hap[m] = {hA, hB} of unit q^m (pure-VALU DPP, within 8-lane slot)
            const float2v hap0 = (float2v){hA, hB};
            const float2v hap1 = (float2v){dppf<0xB1>(hA), dppf<0xB1>(hB)};
            const float2v hap2 = (float2v){dppf<0x4E>(hA), dppf<0x4E>(hB)};
            const float2v hap3 = (float2v){dppf<0x1B>(hA), dppf<0x1B>(hB)};
            const float2v hap7 = (float2v){dppf<0x141>(hA), dppf<0x141>(hB)};
            const float2v hap6 = (float2v){dppf<0x141>(hap1.x), dppf<0x141>(hap1.y)};
            const float2v hap5 = (float2v){dppf<0x141>(hap2.x), dppf<0x141>(hap2.y)};
            const float2v hap4 = (float2v){dppf<0x141>(hap3.x), dppf<0x141>(hap3.y)};

            float2v gg[4];
            #pragma unroll
            for (int g = 0; g < 4; ++g) {
                float2v a = pk_lo3(P[g][0], xs[0], bias[g]);
                a = pk_hi(a, P[g][0], xs[1]);
                a = pk_lo(a, P[g][1], xs[2]);
                a = pk_hi(a, P[g][1], xs[3]);
                a = pk_lo(a, P[g][2], xs[4]);
                a = pk_hi(a, P[g][2], hap0);
                a = pk_lo(a, P[g][3], hap1);
                a = pk_hi(a, P[g][3], hap2);
                a = pk_lo(a, P[g][4], hap3);
                a = pk_hi(a, P[g][4], hap4);
                a = pk_lo(a, P[g][5], hap5);
                a = pk_hi(a, P[g][5], hap6);
                a = pk_lo(a, P[g][6], hap7);
                gg[g] = a;
            }

            // activations, combined-denominator form (8 trans/unit/batch):
            // sig(i)*tanh(g) = (Eg-1) / ((1+Ei)(1+Eg));  h = so*tanh(c) = (Ec-1)/((1+Eo)(1+Ec))
            {
                const float Ei = fexp2(gg[0].x), Ef = fexp2(gg[1].x);
                const float Eg = fexp2(gg[2].x), Eo = fexp2(gg[3].x);
                const float sf  = frcp(1.0f + Ef);
                const float rig = frcp((1.0f + Ei) * (1.0f + Eg));
                cA = fmaf(sf, cA, (Eg - 1.0f) * rig);
                const float Ec  = fexp2(cA * L2E2);
                const float roc = frcp((1.0f + Eo) * (1.0f + Ec));
                hA = (Ec - 1.0f) * roc;
            }
            {
                const float Ei = fexp2(gg[0].y), Ef = fexp2(gg[1].y);
                const float Eg = fexp2(gg[2].y), Eo = fexp2(gg[3].y);
                const float sf  = frcp(1.0f + Ef);
                const float rig = frcp((1.0f + Ei) * (1.0f + Eg));
                cB = fmaf(sf, cB, (Eg - 1.0f) * rig);
                const float Ec  = fexp2(cB * L2E2);
                const float roc = frcp((1.0f + Eo) * (1.0f + Ec));
                hB = (Ec - 1.0f) * roc;
            }

            const float fw = s_fc[t * HID + q];
            accA = fmaf(hA, fw, accA);
            accB = fmaf(hB, fw, accB);
        }

        #pragma unroll
        for (int k = 0; k < 5; ++k) { curA[k] = nxtA[k]; curB[k] = nxtB[k]; }
    }

    // reduce over the 8 units of the slot (lane^1, ^2, ^7 completes the sum)
    accA += dppf<0xB1>(accA); accA += dppf<0x4E>(accA); accA += dppf<0x141>(accA);
    accB += dppf<0xB1>(accB); accB += dppf<0x4E>(accB); accB += dppf<0x141>(accB);
    if (q == 0) {
        out[b0] = accA + fc_b[0];
        if (b0 + 1 < B) out[b0 + 1] = accB + fc_b[0];
    }
}

extern "C" void kernel_launch(void* const* d_in, const int* in_sizes, int n_in,
                              void* d_out, int out_size, void* d_ws, size_t ws_size,
                              hipStream_t stream) {
    const float* x    = (const float*)d_in[0];
    const float* W_ih = (const float*)d_in[1];
    const float* W_hh = (const float*)d_in[2];
    const float* b_ih = (const float*)d_in[3];
    const float* b_hh = (const float*)d_in[4];
    const float* fc_W = (const float*)d_in[5];
    const float* fc_b = (const float*)d_in[6];
    float* out = (float*)d_out;

    const int B = in_sizes[0] / (TT * II);
    const int grid = (B + 15) / 16;   // 16 batches per 64-thread block
    lstm_fused<<<grid, 64, 0, stream>>>(x, W_ih, W_hh, b_ih, b_hh, fc_W, fc_b, out, B);
}

// Round 10
// 98.438 us; speedup vs baseline: 1.0879x; 1.0879x over previous
//
#include <hip/hip_runtime.h>

#define TT 48
#define II 5
#define HID 8

typedef float float2v __attribute__((ext_vector_type(2)));

// quad_perm DPP; 0xB1 = lane^1, 0x4E = lane^2, 0x1B = lane^3; 0x141 = row_half_mirror (lane^7 in 8-lane groups)
template<int CTRL>
__device__ __forceinline__ float dppf(float v) {
    return __int_as_float(__builtin_amdgcn_update_dpp(0, __float_as_int(v), CTRL, 0xF, 0xF, true));
}
__device__ __forceinline__ float fexp2(float x){ float r; asm("v_exp_f32 %0, %1":"=v"(r):"v"(x)); return r; }
__device__ __forceinline__ float frcp(float x){ return __builtin_amdgcn_rcpf(x); }

// packed fp32 fma with weight-half broadcast via op_sel (R3/R7-proven helpers):
// pk_lo: lo += w.lo*z.lo ; hi += w.lo*z.hi
__device__ __forceinline__ float2v pk_lo(float2v acc, float2v w, float2v z) {
    asm("v_pk_fma_f32 %0, %1, %2, %0 op_sel_hi:[0,1,1]" : "+v"(acc) : "v"(w), "v"(z));
    return acc;
}
// pk_hi: lo += w.hi*z.lo ; hi += w.hi*z.hi
__device__ __forceinline__ float2v pk_hi(float2v acc, float2v w, float2v z) {
    asm("v_pk_fma_f32 %0, %1, %2, %0 op_sel:[1,0,0] op_sel_hi:[1,1,1]" : "+v"(acc) : "v"(w), "v"(z));
    return acc;
}
// d = {w.lo*z.lo + b.lo, w.lo*z.hi + b.hi}
__device__ __forceinline__ float2v pk_lo3(float2v w, float2v z, float2v b) {
    float2v d;
    asm("v_pk_fma_f32 %0, %1, %2, %3 op_sel_hi:[0,1,1]" : "=v"(d) : "v"(w), "v"(z), "v"(b));
    return d;
}
__device__ __forceinline__ void pin2(float2v& v) { asm("" : "+v"(v)); }

// 256-thread blocks (4 waves). In-wave: q = lane&7 (unit), slot = lane>>3 -> batch pair.
// Per lane: unit q's weights in 28 float2v pairs; two batch recurrences in pk halves.
// amdgpu_waves_per_eu(4): min 4 waves/EU -> VGPR cap 128 (design ~114 fits) ->
// weights register-resident AND 4 waves resident to hide the serial
// dpp->pk->exp->rcp->exp->rcp chain (R7: 1.7 waves/SIMD -> 30% issue stall).
__global__ __attribute__((amdgpu_flat_work_group_size(256, 256), amdgpu_waves_per_eu(4)))
void lstm_fused(
    const float* __restrict__ x,
    const float* __restrict__ W_ih,
    const float* __restrict__ W_hh,
    const float* __restrict__ b_ih,
    const float* __restrict__ b_hh,
    const float* __restrict__ fc_W,
    const float* __restrict__ fc_b,
    float* __restrict__ out, int B)
{
    __shared__ float s_fc[TT * HID];
    const int tid = threadIdx.x;
    for (int i = tid; i < TT * HID; i += 256) s_fc[i] = fc_W[i];
    __syncthreads();

    const int q    = tid & 7;
    const int slot = tid >> 3;                 // 0..31 across the block
    const int b0   = (blockIdx.x * 32 + slot) * 2;
    if (b0 >= B) return;

    const float L2E  = 1.44269504088896340736f;
    const float L2E2 = 2.0f * L2E;
    // i,f,o rows prescaled by -log2e (E = exp2(s) = e^{-v}); g rows by +2log2e (E = e^{2v}).
    const float sc[4] = {-L2E, -L2E, L2E2, -L2E};

    // ---- weights: 7 pairs per gate; slots = [x0..x4, h_{q^0}..h_{q^7}] ----
    float2v P[4][7], bias[4];
    #pragma unroll
    for (int g = 0; g < 4; ++g) {
        const int row = g * 8 + q;
        const float s = sc[g];
        P[g][0] = (float2v){s * W_ih[row * II + 0], s * W_ih[row * II + 1]};
        P[g][1] = (float2v){s * W_ih[row * II + 2], s * W_ih[row * II + 3]};
        P[g][2] = (float2v){s * W_ih[row * II + 4], s * W_hh[row * HID + (q ^ 0)]};
        P[g][3] = (float2v){s * W_hh[row * HID + (q ^ 1)], s * W_hh[row * HID + (q ^ 2)]};
        P[g][4] = (float2v){s * W_hh[row * HID + (q ^ 3)], s * W_hh[row * HID + (q ^ 4)]};
        P[g][5] = (float2v){s * W_hh[row * HID + (q ^ 5)], s * W_hh[row * HID + (q ^ 6)]};
        P[g][6] = (float2v){s * W_hh[row * HID + (q ^ 7)], 0.0f};
        const float bb = s * (b_ih[row] + b_hh[row]);
        bias[g] = (float2v){bb, bb};
        #pragma unroll
        for (int j = 0; j < 7; ++j) pin2(P[g][j]);
        pin2(bias[g]);
    }

    const float2* xA = reinterpret_cast<const float2*>(x + (size_t)b0 * (TT * II));
    const float2* xB = reinterpret_cast<const float2*>(x + (size_t)(b0 + 1) * (TT * II));

    float2 curA[5], curB[5], nxtA[5], nxtB[5];   // one chunk = 10 floats = 2 steps
    #pragma unroll
    for (int k = 0; k < 5; ++k) { curA[k] = xA[k]; curB[k] = xB[k]; }

    float hA = 0.f, hB = 0.f, cA = 0.f, cB = 0.f, accA = 0.f, accB = 0.f;

    #pragma unroll 1
    for (int ch = 0; ch < 24; ++ch) {
        const int nc = (ch < 23) ? ch + 1 : 23;   // clamped, always-initialized prefetch
        #pragma unroll
        for (int k = 0; k < 5; ++k) { nxtA[k] = xA[nc * 5 + k]; nxtB[k] = xB[nc * 5 + k]; }

        #pragma unroll
        for (int s2 = 0; s2 < 2; ++s2) {
            const int t = ch * 2 + s2;

            // data pairs for this step's 5 x slots ({batchA, batchB})
            float2v xs[5];
            #pragma unroll
            for (int i = 0; i < 5; ++i) {
                const int idx = s2 * 5 + i;
                const float a = (idx & 1) ? curA[idx >> 1].y : curA[idx >> 1].x;
                const float b = (idx & 1) ? curB[idx >> 1].y : curB[idx >> 1].x;
                xs[i] = (float2v){a, b};
            }

            // h gather: hap[m] = {hA, hB} of unit q^m (pure-VALU DPP, within 8-lane slot)
            const float2v hap0 = (float2v){hA, hB};
            const float2v hap1 = (float2v){dppf<0xB1>(hA), dppf<0xB1>(hB)};
            const float2v hap2 = (float2v){dppf<0x4E>(hA), dppf<0x4E>(hB)};
            const float2v hap3 = (float2v){dppf<0x1B>(hA), dppf<0x1B>(hB)};
            const float2v hap7 = (float2v){dppf<0x141>(hA), dppf<0x141>(hB)};
            const float2v hap6 = (float2v){dppf<0x141>(hap1.x), dppf<0x141>(hap1.y)};
            const float2v hap5 = (float2v){dppf<0x141>(hap2.x), dppf<0x141>(hap2.y)};
            const float2v hap4 = (float2v){dppf<0x141>(hap3.x), dppf<0x141>(hap3.y)};

            float2v gg[4];
            #pragma unroll
            for (int g = 0; g < 4; ++g) {
                float2v a = pk_lo3(P[g][0], xs[0], bias[g]);
                a = pk_hi(a, P[g][0], xs[1]);
                a = pk_lo(a, P[g][1], xs[2]);
                a = pk_hi(a, P[g][1], xs[3]);
                a = pk_lo(a, P[g][2], xs[4]);
                a = pk_hi(a, P[g][2], hap0);
                a = pk_lo(a, P[g][3], hap1);
                a = pk_hi(a, P[g][3], hap2);
                a = pk_lo(a, P[g][4], hap3);
                a = pk_hi(a, P[g][4], hap4);
                a = pk_lo(a, P[g][5], hap5);
                a = pk_hi(a, P[g][5], hap6);
                a = pk_lo(a, P[g][6], hap7);
                gg[g] = a;
            }

            // activations, 2-rcp combined-denominator form (7 trans/unit/batch):
            // c' = c/Df + (Eg-1)/(Di*Dg) = (Pig*c + (Eg-1)*Df) * rcp(Pig*Df)
            // h  = (Ec-1) / ((1+Eo)(1+Ec))
            {
                const float Ei = fexp2(gg[0].x), Ef = fexp2(gg[1].x);
                const float Eg = fexp2(gg[2].x), Eo = fexp2(gg[3].x);
                const float Di = 1.f + Ei, Df = 1.f + Ef, Dg = 1.f + Eg;
                const float Pig = Di * Dg;
                const float R3  = frcp(Pig * Df);
                cA = fmaf(Pig, cA, fmaf(Eg, Df, -Df)) * R3;
                const float Ec  = fexp2(cA * L2E2);
                const float Ro  = frcp((1.f + Eo) * (1.f + Ec));
                hA = fmaf(Ec, Ro, -Ro);
            }
            {
                const float Ei = fexp2(gg[0].y), Ef = fexp2(gg[1].y);
                const float Eg = fexp2(gg[2].y), Eo = fexp2(gg[3].y);
                const float Di = 1.f + Ei, Df = 1.f + Ef, Dg = 1.f + Eg;
                const float Pig = Di * Dg;
                const float R3  = frcp(Pig * Df);
                cB = fmaf(Pig, cB, fmaf(Eg, Df, -Df)) * R3;
                const float Ec  = fexp2(cB * L2E2);
                const float Ro  = frcp((1.f + Eo) * (1.f + Ec));
                hB = fmaf(Ec, Ro, -Ro);
            }

            const float fw = s_fc[t * HID + q];
            accA = fmaf(hA, fw, accA);
            accB = fmaf(hB, fw, accB);
        }

        #pragma unroll
        for (int k = 0; k < 5; ++k) { curA[k] = nxtA[k]; curB[k] = nxtB[k]; }
    }

    // reduce over the 8 units of the slot (lane^1, ^2, ^7 completes the sum)
    accA += dppf<0xB1>(accA); accA += dppf<0x4E>(accA); accA += dppf<0x141>(accA);
    accB += dppf<0xB1>(accB); accB += dppf<0x4E>(accB); accB += dppf<0x141>(accB);
    if (q == 0) {
        out[b0] = accA + fc_b[0];
        if (b0 + 1 < B) out[b0 + 1] = accB + fc_b[0];
    }
}

extern "C" void kernel_launch(void* const* d_in, const int* in_sizes, int n_in,
                              void* d_out, int out_size, void* d_ws, size_t ws_size,
                              hipStream_t stream) {
    const float* x    = (const float*)d_in[0];
    const float* W_ih = (const float*)d_in[1];
    const float* W_hh = (const float*)d_in[2];
    const float* b_ih = (const float*)d_in[3];
    const float* b_hh = (const float*)d_in[4];
    const float* fc_W = (const float*)d_in[5];
    const float* fc_b = (const float*)d_in[6];
    float* out = (float*)d_out;

    const int B = in_sizes[0] / (TT * II);
    const int grid = (B + 63) / 64;   // 64 batches per 256-thread block
    lstm_fused<<<grid, 256, 0, stream>>>(x, W_ih, W_hh, b_ih, b_hh, fc_W, fc_b, out, B);
}